// Round 2
// baseline (51.709 us; speedup 1.0000x reference)
//
#include <hip/hip_runtime.h>

#define N_MEM 8
#define BSZ   64
#define DK    256
#define DV    256

typedef float f32x4 __attribute__((ext_vector_type(4)));

// One block per (n, b) pair: processes the 256x256 f32 state matrix.
// new_state[k][v] = lam * state[k][v] + (rho*alpha) * key[k] * value[v]
// readout[v]     += query[k] * new_state[k][v]
__global__ __launch_bounds__(1024) void mom_kernel(
    const float* __restrict__ states,   // [N, B, DK, DV]
    const float* __restrict__ key,      // [B, DK]
    const float* __restrict__ value,    // [B, DV]
    const float* __restrict__ alpha,    // [B, 1]
    const float* __restrict__ rho,      // [B, N]
    const float* __restrict__ lam,      // [B, N]
    const float* __restrict__ query,    // [B, DK]
    float* __restrict__ out_states,     // [N, B, DK, DV]
    float* __restrict__ out_read)       // [N, B, DV]
{
    const int bid = blockIdx.x;          // n*B + b
    const int n   = bid >> 6;            // bid / 64
    const int b   = bid & 63;            // bid % 64
    const int t   = threadIdx.x;

    __shared__ float s_key[DK];
    __shared__ float s_q[DK];
    __shared__ f32x4 s_val4[DV / 4];
    __shared__ f32x4 s_red[1024];

    // Stage the per-b rows into LDS (once per block).
    if (t < DK) {
        s_key[t] = key[b * DK + t];
        s_q[t]   = query[b * DK + t];
    } else if (t < DK + DV / 4) {
        const int v4 = t - DK;
        s_val4[v4] = reinterpret_cast<const f32x4*>(value + (size_t)b * DV)[v4];
    }
    const float lam_s = lam[b * N_MEM + n];
    const float w_s   = rho[b * N_MEM + n] * alpha[b];
    __syncthreads();

    // Each thread owns a fixed v-column (4 floats): flat float4 index
    // idx = t + it*1024 -> v4 = idx & 63 = t & 63 (const), k = (t>>6) + it*16.
    const int   v4  = t & 63;
    const f32x4 val = s_val4[v4];
    const int   k0  = t >> 6;

    // Hoist all LDS reads out of the hot loop: per-thread k-coefficients
    // (compile-time indexed so they stay in VGPRs, not scratch).
    float kw[16], qv[16];
#pragma unroll
    for (int it = 0; it < 16; ++it) {
        kw[it] = w_s * s_key[k0 + it * 16];
        qv[it] = s_q[k0 + it * 16];
    }

    const size_t base = (size_t)bid * (DK * DV);
    const f32x4* __restrict__ sp = reinterpret_cast<const f32x4*>(states + base);
    f32x4*       __restrict__ op = reinterpret_cast<f32x4*>(out_states + base);

    f32x4 racc = (f32x4)(0.f);

#pragma unroll
    for (int it = 0; it < 16; ++it) {
        const int idx = t + it * 1024;
        const f32x4 s = __builtin_nontemporal_load(&sp[idx]);
        const f32x4 ns = lam_s * s + kw[it] * val;
        __builtin_nontemporal_store(ns, &op[idx]);
        racc += qv[it] * ns;
    }

    // Reduce readout across the 16 threads sharing each v-column.
    s_red[t] = racc;
    __syncthreads();
    if (t < 64) {
        f32x4 acc = s_red[t];
#pragma unroll
        for (int g = 1; g < 16; ++g)
            acc += s_red[t + g * 64];
        reinterpret_cast<f32x4*>(out_read + (size_t)bid * DV)[t] = acc;
    }
}

extern "C" void kernel_launch(void* const* d_in, const int* in_sizes, int n_in,
                              void* d_out, int out_size, void* d_ws, size_t ws_size,
                              hipStream_t stream) {
    const float* states = (const float*)d_in[0];
    const float* key    = (const float*)d_in[1];
    const float* value  = (const float*)d_in[2];
    const float* alpha  = (const float*)d_in[3];
    const float* rho    = (const float*)d_in[4];
    const float* lam    = (const float*)d_in[5];
    const float* query  = (const float*)d_in[6];

    float* out_states = (float*)d_out;                               // N*B*DK*DV
    float* out_read   = out_states + (size_t)N_MEM * BSZ * DK * DV;  // N*B*DV

    dim3 grid(N_MEM * BSZ);
    dim3 block(1024);
    mom_kernel<<<grid, block, 0, stream>>>(states, key, value, alpha, rho, lam,
                                           query, out_states, out_read);
}

// Round 3
// 48.157 us; speedup vs baseline: 1.0738x; 1.0738x over previous
//
#include <hip/hip_runtime.h>

#define N_MEM 8
#define BSZ   64
#define DK    256
#define DV    256

typedef float f32x4 __attribute__((ext_vector_type(4)));

// One block per (n, b) pair: processes the 256x256 f32 state matrix.
// new_state[k][v] = lam * state[k][v] + (rho*alpha) * key[k] * value[v]
// readout[v]     += query[k] * new_state[k][v]
//
// Loads are CACHED (states may stay L3-resident across graph replays);
// stores are NON-TEMPORAL (write stream should not evict the read stream).
__global__ __launch_bounds__(1024) void mom_kernel(
    const float* __restrict__ states,   // [N, B, DK, DV]
    const float* __restrict__ key,      // [B, DK]
    const float* __restrict__ value,    // [B, DV]
    const float* __restrict__ alpha,    // [B, 1]
    const float* __restrict__ rho,      // [B, N]
    const float* __restrict__ lam,      // [B, N]
    const float* __restrict__ query,    // [B, DK]
    float* __restrict__ out_states,     // [N, B, DK, DV]
    float* __restrict__ out_read)       // [N, B, DV]
{
    const int bid = blockIdx.x;          // n*B + b
    const int n   = bid >> 6;            // bid / 64
    const int b   = bid & 63;            // bid % 64
    const int t   = threadIdx.x;

    __shared__ float s_key[DK];
    __shared__ float s_q[DK];
    __shared__ f32x4 s_val4[DV / 4];
    __shared__ f32x4 s_red[1024];

    // Stage the per-b rows into LDS (once per block).
    if (t < DK) {
        s_key[t] = key[b * DK + t];
        s_q[t]   = query[b * DK + t];
    } else if (t < DK + DV / 4) {
        const int v4 = t - DK;
        s_val4[v4] = reinterpret_cast<const f32x4*>(value + (size_t)b * DV)[v4];
    }
    const float lam_s = lam[b * N_MEM + n];
    const float w_s   = rho[b * N_MEM + n] * alpha[b];
    __syncthreads();

    // Each thread owns a fixed v-column (4 floats): flat float4 index
    // idx = t + it*1024 -> v4 = idx & 63 = t & 63 (const), k = (t>>6) + it*16.
    const int   v4  = t & 63;
    const f32x4 val = s_val4[v4];
    const int   k0  = t >> 6;

    // Hoist all LDS reads out of the hot loop (compile-time indexed -> VGPRs).
    float kw[16], qv[16];
#pragma unroll
    for (int it = 0; it < 16; ++it) {
        kw[it] = w_s * s_key[k0 + it * 16];
        qv[it] = s_q[k0 + it * 16];
    }

    const size_t base = (size_t)bid * (DK * DV);
    const f32x4* __restrict__ sp = reinterpret_cast<const f32x4*>(states + base);
    f32x4*       __restrict__ op = reinterpret_cast<f32x4*>(out_states + base);

    f32x4 racc = (f32x4)(0.f);

#pragma unroll
    for (int it = 0; it < 16; ++it) {
        const int idx = t + it * 1024;
        const f32x4 s = sp[idx];                       // cached load
        const f32x4 ns = lam_s * s + kw[it] * val;
        __builtin_nontemporal_store(ns, &op[idx]);     // NT store
        racc += qv[it] * ns;
    }

    // Reduce readout across the 16 threads sharing each v-column.
    s_red[t] = racc;
    __syncthreads();
    if (t < 64) {
        f32x4 acc = s_red[t];
#pragma unroll
        for (int g = 1; g < 16; ++g)
            acc += s_red[t + g * 64];
        reinterpret_cast<f32x4*>(out_read + (size_t)bid * DV)[t] = acc;
    }
}

extern "C" void kernel_launch(void* const* d_in, const int* in_sizes, int n_in,
                              void* d_out, int out_size, void* d_ws, size_t ws_size,
                              hipStream_t stream) {
    const float* states = (const float*)d_in[0];
    const float* key    = (const float*)d_in[1];
    const float* value  = (const float*)d_in[2];
    const float* alpha  = (const float*)d_in[3];
    const float* rho    = (const float*)d_in[4];
    const float* lam    = (const float*)d_in[5];
    const float* query  = (const float*)d_in[6];

    float* out_states = (float*)d_out;                               // N*B*DK*DV
    float* out_read   = out_states + (size_t)N_MEM * BSZ * DK * DV;  // N*B*DV

    dim3 grid(N_MEM * BSZ);
    dim3 block(1024);
    mom_kernel<<<grid, block, 0, stream>>>(states, key, value, alpha, rho, lam,
                                           query, out_states, out_read);
}

// Round 4
// 46.789 us; speedup vs baseline: 1.1051x; 1.0292x over previous
//
#include <hip/hip_runtime.h>

#define N_MEM 8
#define BSZ   64
#define DK    256
#define DV    256

typedef float f32x4 __attribute__((ext_vector_type(4)));

// ---------------------------------------------------------------------------
// Fine-grained path: 2048 blocks x 256 threads. Block = (n, b, k-chunk of 64
// rows). Partial readouts go to d_ws; a second tiny kernel reduces them.
// ---------------------------------------------------------------------------
__global__ __launch_bounds__(256) void mom_kernel_fine(
    const float* __restrict__ states,   // [N, B, DK, DV]
    const float* __restrict__ key,      // [B, DK]
    const float* __restrict__ value,    // [B, DV]
    const float* __restrict__ alpha,    // [B, 1]
    const float* __restrict__ rho,      // [B, N]
    const float* __restrict__ lam,      // [B, N]
    const float* __restrict__ query,    // [B, DK]
    float* __restrict__ out_states,     // [N, B, DK, DV]
    float* __restrict__ ws_partial)     // [2048, DV]
{
    const int bid4  = blockIdx.x;        // (n*B + b)*4 + chunk
    const int group = bid4 >> 2;         // n*B + b
    const int chunk = bid4 & 3;          // which 64-row k-chunk
    const int n     = group >> 6;
    const int b     = group & 63;
    const int t     = threadIdx.x;

    __shared__ float s_key[64];          // this chunk's 64 key entries
    __shared__ float s_q[64];            // this chunk's 64 query entries
    __shared__ f32x4 s_val4[DV / 4];     // full value row
    __shared__ f32x4 s_red[256];

    if (t < 64) {
        const int kg = chunk * 64 + t;
        s_key[t] = key[b * DK + kg];
        s_q[t]   = query[b * DK + kg];
    } else if (t < 128) {
        const int v4 = t - 64;
        s_val4[v4] = reinterpret_cast<const f32x4*>(value + (size_t)b * DV)[v4];
    }
    const float lam_s = lam[b * N_MEM + n];
    const float w_s   = rho[b * N_MEM + n] * alpha[b];
    __syncthreads();

    // flat float4 index within chunk: idx = t + it*256
    //   v4 = idx & 63 = t & 63 (const);  k_local = (t>>6) + it*4
    const int   v4  = t & 63;
    const f32x4 val = s_val4[v4];
    const int   k0  = t >> 6;

    float kw[16], qv[16];
#pragma unroll
    for (int it = 0; it < 16; ++it) {
        kw[it] = w_s * s_key[k0 + it * 4];
        qv[it] = s_q[k0 + it * 4];
    }

    const size_t base = (size_t)group * (DK * DV) + (size_t)chunk * (64 * DV);
    const f32x4* __restrict__ sp = reinterpret_cast<const f32x4*>(states + base);
    f32x4*       __restrict__ op = reinterpret_cast<f32x4*>(out_states + base);

    f32x4 racc = (f32x4)(0.f);

#pragma unroll
    for (int it = 0; it < 16; ++it) {
        const int idx = t + it * 256;
        const f32x4 s  = sp[idx];                      // cached load (L3 reuse)
        const f32x4 ns = lam_s * s + kw[it] * val;
        __builtin_nontemporal_store(ns, &op[idx]);     // NT store
        racc += qv[it] * ns;
    }

    // Reduce the 4 k-row-groups within the block -> 256-float partial.
    s_red[t] = racc;
    __syncthreads();
    if (t < 64) {
        f32x4 acc = s_red[t];
#pragma unroll
        for (int g = 1; g < 4; ++g)
            acc += s_red[t + g * 64];
        reinterpret_cast<f32x4*>(ws_partial + (size_t)bid4 * DV)[t] = acc;
    }
}

__global__ __launch_bounds__(64) void mom_reduce(
    const float* __restrict__ ws_partial,  // [2048, DV]
    float* __restrict__ out_read)          // [N, B, DV] = [512, DV]
{
    const int g = blockIdx.x;             // n*B + b
    const int t = threadIdx.x;            // v4 index
    const f32x4* wp = reinterpret_cast<const f32x4*>(ws_partial);
    f32x4 acc = (f32x4)(0.f);
#pragma unroll
    for (int c = 0; c < 4; ++c)
        acc += wp[(size_t)(g * 4 + c) * (DV / 4) + t];
    reinterpret_cast<f32x4*>(out_read)[(size_t)g * (DV / 4) + t] = acc;
}

// ---------------------------------------------------------------------------
// Fallback (round-3 structure): single kernel, 512 blocks x 1024 threads.
// Used only if ws_size is too small for partials.
// ---------------------------------------------------------------------------
__global__ __launch_bounds__(1024) void mom_kernel_mono(
    const float* __restrict__ states, const float* __restrict__ key,
    const float* __restrict__ value, const float* __restrict__ alpha,
    const float* __restrict__ rho, const float* __restrict__ lam,
    const float* __restrict__ query, float* __restrict__ out_states,
    float* __restrict__ out_read)
{
    const int bid = blockIdx.x;
    const int n   = bid >> 6;
    const int b   = bid & 63;
    const int t   = threadIdx.x;

    __shared__ float s_key[DK];
    __shared__ float s_q[DK];
    __shared__ f32x4 s_val4[DV / 4];
    __shared__ f32x4 s_red[1024];

    if (t < DK) {
        s_key[t] = key[b * DK + t];
        s_q[t]   = query[b * DK + t];
    } else if (t < DK + DV / 4) {
        s_val4[t - DK] = reinterpret_cast<const f32x4*>(value + (size_t)b * DV)[t - DK];
    }
    const float lam_s = lam[b * N_MEM + n];
    const float w_s   = rho[b * N_MEM + n] * alpha[b];
    __syncthreads();

    const int   v4  = t & 63;
    const f32x4 val = s_val4[v4];
    const int   k0  = t >> 6;

    float kw[16], qv[16];
#pragma unroll
    for (int it = 0; it < 16; ++it) {
        kw[it] = w_s * s_key[k0 + it * 16];
        qv[it] = s_q[k0 + it * 16];
    }

    const size_t base = (size_t)bid * (DK * DV);
    const f32x4* __restrict__ sp = reinterpret_cast<const f32x4*>(states + base);
    f32x4*       __restrict__ op = reinterpret_cast<f32x4*>(out_states + base);

    f32x4 racc = (f32x4)(0.f);
#pragma unroll
    for (int it = 0; it < 16; ++it) {
        const int idx = t + it * 1024;
        const f32x4 s  = sp[idx];
        const f32x4 ns = lam_s * s + kw[it] * val;
        __builtin_nontemporal_store(ns, &op[idx]);
        racc += qv[it] * ns;
    }

    s_red[t] = racc;
    __syncthreads();
    if (t < 64) {
        f32x4 acc = s_red[t];
#pragma unroll
        for (int g = 1; g < 16; ++g)
            acc += s_red[t + g * 64];
        reinterpret_cast<f32x4*>(out_read + (size_t)bid * DV)[t] = acc;
    }
}

extern "C" void kernel_launch(void* const* d_in, const int* in_sizes, int n_in,
                              void* d_out, int out_size, void* d_ws, size_t ws_size,
                              hipStream_t stream) {
    const float* states = (const float*)d_in[0];
    const float* key    = (const float*)d_in[1];
    const float* value  = (const float*)d_in[2];
    const float* alpha  = (const float*)d_in[3];
    const float* rho    = (const float*)d_in[4];
    const float* lam    = (const float*)d_in[5];
    const float* query  = (const float*)d_in[6];

    float* out_states = (float*)d_out;                               // N*B*DK*DV
    float* out_read   = out_states + (size_t)N_MEM * BSZ * DK * DV;  // N*B*DV

    const size_t need_ws = (size_t)2048 * DV * sizeof(float);        // 2 MiB
    if (ws_size >= need_ws) {
        float* ws_partial = (float*)d_ws;
        mom_kernel_fine<<<dim3(2048), dim3(256), 0, stream>>>(
            states, key, value, alpha, rho, lam, query, out_states, ws_partial);
        mom_reduce<<<dim3(512), dim3(64), 0, stream>>>(ws_partial, out_read);
    } else {
        mom_kernel_mono<<<dim3(512), dim3(1024), 0, stream>>>(
            states, key, value, alpha, rho, lam, query, out_states, out_read);
    }
}